// Round 1
// baseline (564.911 us; speedup 1.0000x reference)
//
#include <hip/hip_runtime.h>
#include <hip/hip_bf16.h>

#define BATCH 16
#define SEQ   577
#define CDIM  768
#define HEADS 12
#define DHEAD 64
#define FFDIM 3072
#define MROWS (BATCH*SEQ)   // 9232

typedef __bf16 bf16x8 __attribute__((ext_vector_type(8)));
typedef float  f32x4  __attribute__((ext_vector_type(4)));
typedef unsigned short u16x8 __attribute__((ext_vector_type(8)));

__device__ __forceinline__ unsigned short f2bf(float f) {
    unsigned u = __builtin_bit_cast(unsigned, f);
    unsigned r = (u + 0x7FFFu + ((u >> 16) & 1u)) >> 16;
    return (unsigned short)r;
}
__device__ __forceinline__ float bf2f(unsigned short s) {
    return __builtin_bit_cast(float, (unsigned)s << 16);
}
__device__ __forceinline__ float gelu_f(float v) {
    return 0.5f * v * (1.f + erff(v * 0.7071067811865475f));
}

// ---------------- weight conversion: fp32 -> bf16, transposed to [out][in] ----
#define S0 (2304*768)
#define S1 (768*768)
#define S2 (768*3072)
#define S3 (3072*768)
#define STOT (S0+S1+S2+S3)

__global__ __launch_bounds__(256) void convert_w(
    const float* __restrict__ wq, const float* __restrict__ wk, const float* __restrict__ wv,
    const float* __restrict__ wo, const float* __restrict__ w1, const float* __restrict__ w2,
    const float* __restrict__ bq, const float* __restrict__ bk, const float* __restrict__ bv,
    unsigned short* __restrict__ wqkvT, unsigned short* __restrict__ woT,
    unsigned short* __restrict__ w1T, unsigned short* __restrict__ w2T,
    float* __restrict__ bqkv)
{
    for (size_t id = (size_t)blockIdx.x * 256 + threadIdx.x; id < STOT + 2304; id += (size_t)gridDim.x * 256) {
        if (id < S0) {
            int n = (int)(id / 768), k = (int)(id % 768);
            const float* w = (n < 768) ? wq : (n < 1536) ? wk : wv;
            int c = (n < 768) ? n : (n < 1536) ? n - 768 : n - 1536;
            wqkvT[id] = f2bf(w[(size_t)k * 768 + c]);
        } else if (id < S0 + S1) {
            size_t i2 = id - S0; int n = (int)(i2 / 768), k = (int)(i2 % 768);
            woT[i2] = f2bf(wo[(size_t)k * 768 + n]);
        } else if (id < S0 + S1 + S2) {
            size_t i3 = id - S0 - S1; int n = (int)(i3 / 768), k = (int)(i3 % 768);
            w1T[i3] = f2bf(w1[(size_t)k * 3072 + n]);
        } else if (id < STOT) {
            size_t i4 = id - S0 - S1 - S2; int n = (int)(i4 / 3072), k = (int)(i4 % 3072);
            w2T[i4] = f2bf(w2[(size_t)k * 768 + n]);
        } else {
            int c = (int)(id - STOT);
            float v = (c < 768) ? bq[c] : (c < 1536) ? bk[c - 768] : bv[c - 1536];
            bqkv[c] = v;
        }
    }
}

// ---------------- LayerNorm (row of 768) -> bf16 ------------------------------
__global__ __launch_bounds__(256) void ln_bf16(
    const float* __restrict__ x, const float* __restrict__ g, const float* __restrict__ b,
    unsigned short* __restrict__ out)
{
    int row = blockIdx.x;
    int t = threadIdx.x;
    const float* xr = x + (size_t)row * CDIM;
    float v0 = xr[t], v1 = xr[t + 256], v2 = xr[t + 512];
    float s = v0 + v1 + v2;
    float q = v0 * v0 + v1 * v1 + v2 * v2;
    __shared__ float red[8];
    for (int o = 32; o > 0; o >>= 1) { s += __shfl_down(s, o); q += __shfl_down(q, o); }
    int wid = t >> 6;
    if ((t & 63) == 0) { red[wid] = s; red[4 + wid] = q; }
    __syncthreads();
    if (t == 0) {
        float S = red[0] + red[1] + red[2] + red[3];
        float Q = red[4] + red[5] + red[6] + red[7];
        float mu = S * (1.f / CDIM);
        float var = Q * (1.f / CDIM) - mu * mu;
        red[0] = mu; red[1] = rsqrtf(var + 1e-5f);
    }
    __syncthreads();
    float mu = red[0], rs = red[1];
    unsigned short* orow = out + (size_t)row * CDIM;
    orow[t]       = f2bf((v0 - mu) * rs * g[t]       + b[t]);
    orow[t + 256] = f2bf((v1 - mu) * rs * g[t + 256] + b[t + 256]);
    orow[t + 512] = f2bf((v2 - mu) * rs * g[t + 512] + b[t + 512]);
}

// ---------------- GEMM: C[M,N] = A[M,K](bf16) * Bt[N,K]^T(bf16) + bias --------
// EPI 0: store bf16.  EPI 1: float out = resid + v.  EPI 2: store bf16(gelu(v)).
template<int EPI>
__global__ __launch_bounds__(256) void gemm64(
    const unsigned short* __restrict__ A, const unsigned short* __restrict__ Bt,
    const float* __restrict__ bias, void* __restrict__ Cout,
    const float* __restrict__ resid, int M, int Nn, int K)
{
    __shared__ __align__(16) unsigned short As[64][40];
    __shared__ __align__(16) unsigned short Bs[64][40];

    int t = threadIdx.x;
    int nbase = blockIdx.x * 64;
    int mbase = blockIdx.y * 64;
    int lane = t & 63, w = t >> 6;
    int wm = w >> 1, wn = w & 1;
    int lr = lane & 15, lk = lane >> 4;
    int k0 = lk * 8;

    int sr = t >> 2, skq = (t & 3) * 8;

    f32x4 acc[2][2] = {};

    for (int kt = 0; kt < K; kt += 32) {
        // stage A (64 x 32)
        uint4 av = {0, 0, 0, 0};
        int arow = mbase + sr;
        if (arow < M) av = *(const uint4*)(A + (size_t)arow * K + kt + skq);
        *(uint4*)&As[sr][skq] = av;
        // stage B (Bt rows nbase..nbase+63)
        uint4 bv = *(const uint4*)(Bt + (size_t)(nbase + sr) * K + kt + skq);
        *(uint4*)&Bs[sr][skq] = bv;
        __syncthreads();

        bf16x8 af[2], bf[2];
        af[0] = *(const bf16x8*)&As[wm * 32 + lr][k0];
        af[1] = *(const bf16x8*)&As[wm * 32 + 16 + lr][k0];
        bf[0] = *(const bf16x8*)&Bs[wn * 32 + lr][k0];
        bf[1] = *(const bf16x8*)&Bs[wn * 32 + 16 + lr][k0];
        for (int mi = 0; mi < 2; mi++)
            for (int ni = 0; ni < 2; ni++)
                acc[mi][ni] = __builtin_amdgcn_mfma_f32_16x16x32_bf16(af[mi], bf[ni], acc[mi][ni], 0, 0, 0);
        __syncthreads();
    }

    for (int mi = 0; mi < 2; mi++) {
        for (int ni = 0; ni < 2; ni++) {
            int col = nbase + wn * 32 + ni * 16 + lr;
            float bcol = bias[col];
            for (int i = 0; i < 4; i++) {
                int row = mbase + wm * 32 + mi * 16 + lk * 4 + i;
                if (row >= M) continue;
                float v = acc[mi][ni][i] + bcol;
                if (EPI == 0) {
                    ((unsigned short*)Cout)[(size_t)row * Nn + col] = f2bf(v);
                } else if (EPI == 1) {
                    ((float*)Cout)[(size_t)row * Nn + col] = resid[(size_t)row * Nn + col] + v;
                } else {
                    ((unsigned short*)Cout)[(size_t)row * Nn + col] = f2bf(gelu_f(v));
                }
            }
        }
    }
}

// ---------------- fused attention: per (b,h, 32-q-tile) -----------------------
__global__ __launch_bounds__(256) void attn_kernel(
    const unsigned short* __restrict__ qkv, unsigned short* __restrict__ attno)
{
    int bh = blockIdx.y;
    int b = bh / HEADS, h = bh % HEADS;
    int qt = blockIdx.x;                 // 0..18, rows qt*32..qt*32+31
    int t = threadIdx.x;
    int lane = t & 63, w = t >> 6;
    int lr = lane & 15, lk = lane >> 4, k0 = lk * 8;

    const size_t baseRow = (size_t)b * SEQ;
    const unsigned short* Qp = qkv + baseRow * 2304 + h * 64;
    const unsigned short* Kp = Qp + 768;
    const unsigned short* Vp = Qp + 1536;

    __shared__ __align__(16) unsigned short sSP[32][608];  // scores -> P (bf16)
    __shared__ __align__(16) unsigned short sVt[64][40];   // V^T chunk [d][j]
    __shared__ float sRed[32][8];
    __shared__ float sRowMax[32], sRowSum[32];

    // ---- QK^T scores via MFMA, K read straight from global --------------------
    bf16x8 afr[2][2];
    for (int mi = 0; mi < 2; mi++) {
        int qr = qt * 32 + mi * 16 + lr; if (qr > SEQ - 1) qr = SEQ - 1;
        for (int ks = 0; ks < 2; ks++)
            afr[mi][ks] = *(const bf16x8*)(Qp + (size_t)qr * 2304 + ks * 32 + k0);
    }
    for (int jt = w; jt < 37; jt += 4) {
        f32x4 acc[2] = {};
        int j = jt * 16 + lr; if (j > SEQ - 1) j = SEQ - 1;
        for (int ks = 0; ks < 2; ks++) {
            bf16x8 bfr = *(const bf16x8*)(Kp + (size_t)j * 2304 + ks * 32 + k0);
            for (int mi = 0; mi < 2; mi++)
                acc[mi] = __builtin_amdgcn_mfma_f32_16x16x32_bf16(afr[mi][ks], bfr, acc[mi], 0, 0, 0);
        }
        for (int mi = 0; mi < 2; mi++)
            for (int i = 0; i < 4; i++)
                sSP[mi * 16 + lk * 4 + i][jt * 16 + lr] = f2bf(acc[mi][i] * 0.125f);
    }
    __syncthreads();
    // invalidate j >= 577
    for (int idx = t; idx < 32 * 31; idx += 256) {
        int ri = idx / 31, j = SEQ + idx % 31;
        sSP[ri][j] = 0xFF80;  // -inf bf16
    }
    __syncthreads();

    // ---- softmax over 608 cols (valid < 577), in-place P = exp(s-max) --------
    int tq = t >> 3, tj = t & 7;
    float mx = -1e30f;
    for (int j = tj; j < 608; j += 8) mx = fmaxf(mx, bf2f(sSP[tq][j]));
    sRed[tq][tj] = mx;
    __syncthreads();
    if (tj == 0) {
        float m = sRed[tq][0];
        for (int i = 1; i < 8; i++) m = fmaxf(m, sRed[tq][i]);
        sRowMax[tq] = m;
    }
    __syncthreads();
    float rm = sRowMax[tq];
    float sum = 0.f;
    for (int j = tj; j < 608; j += 8) {
        float p = __expf(bf2f(sSP[tq][j]) - rm);
        sum += p;
        sSP[tq][j] = f2bf(p);
    }
    sRed[tq][tj] = sum;
    __syncthreads();
    if (tj == 0) {
        float s2 = 0.f;
        for (int i = 0; i < 8; i++) s2 += sRed[tq][i];
        sRowSum[tq] = s2;
    }
    __syncthreads();

    // ---- PV via MFMA: o[32][64] = P[32][608] * V[608][64] ---------------------
    f32x4 oacc[2] = {};
    for (int jc = 0; jc < 19; jc++) {
        __syncthreads();
        {
            int jj = t >> 3, dg = (t & 7) * 8;
            int jv = jc * 32 + jj; if (jv > SEQ - 1) jv = SEQ - 1;
            u16x8 vv = *(const u16x8*)(Vp + (size_t)jv * 2304 + dg);
            for (int e = 0; e < 8; e++) sVt[dg + e][jj] = vv[e];
        }
        __syncthreads();
        bf16x8 vb = *(const bf16x8*)&sVt[w * 16 + lr][k0];
        for (int mi = 0; mi < 2; mi++) {
            bf16x8 pa = *(const bf16x8*)&sSP[mi * 16 + lr][jc * 32 + k0];
            oacc[mi] = __builtin_amdgcn_mfma_f32_16x16x32_bf16(pa, vb, oacc[mi], 0, 0, 0);
        }
    }
    for (int mi = 0; mi < 2; mi++) {
        for (int i = 0; i < 4; i++) {
            int ri = mi * 16 + lk * 4 + i;
            int qr = qt * 32 + ri;
            if (qr < SEQ) {
                float ov = oacc[mi][i] / sRowSum[ri];
                attno[(baseRow + qr) * CDIM + h * 64 + w * 16 + lr] = f2bf(ov);
            }
        }
    }
}

// ---------------- host launch --------------------------------------------------
extern "C" void kernel_launch(void* const* d_in, const int* in_sizes, int n_in,
                              void* d_out, int out_size, void* d_ws, size_t ws_size,
                              hipStream_t stream) {
    const float* x     = (const float*)d_in[0];
    const float* ln1_g = (const float*)d_in[2];
    const float* ln1_b = (const float*)d_in[3];
    const float* wq    = (const float*)d_in[4];
    const float* bq    = (const float*)d_in[5];
    const float* wk    = (const float*)d_in[6];
    const float* bk    = (const float*)d_in[7];
    const float* wv    = (const float*)d_in[8];
    const float* bv    = (const float*)d_in[9];
    const float* wo    = (const float*)d_in[10];
    const float* bo    = (const float*)d_in[11];
    const float* ln2_g = (const float*)d_in[12];
    const float* ln2_b = (const float*)d_in[13];
    const float* w1    = (const float*)d_in[14];
    const float* b1    = (const float*)d_in[15];
    const float* w2    = (const float*)d_in[16];
    const float* b2    = (const float*)d_in[17];
    float* out = (float*)d_out;

    char* ws = (char*)d_ws;
    unsigned short* wqkvT = (unsigned short*)(ws + 0);
    unsigned short* woT   = (unsigned short*)(ws + 3538944);
    unsigned short* w1T   = (unsigned short*)(ws + 4718592);
    unsigned short* w2T   = (unsigned short*)(ws + 9437184);
    float*          bqkv  = (float*)         (ws + 14155776);
    unsigned short* qkv   = (unsigned short*)(ws + 14164992);  // 9232 x 2304
    unsigned short* hbuf  = (unsigned short*)(ws + 56706048);  // 9232 x 768
    unsigned short* attno = (unsigned short*)(ws + 70886400);  // 9232 x 768 (reused for h2)
    unsigned short* mid   = (unsigned short*)(ws + 14164992);  // 9232 x 3072 aliases qkv+h (both dead)
    unsigned short* h2    = attno;                              // attno dead after o-proj

    // 1. weights -> bf16 transposed
    convert_w<<<4096, 256, 0, stream>>>(wq, wk, wv, wo, w1, w2, bq, bk, bv,
                                        wqkvT, woT, w1T, w2T, bqkv);
    // 2. LN1
    ln_bf16<<<MROWS, 256, 0, stream>>>(x, ln1_g, ln1_b, hbuf);
    // 3. QKV projection: qkv = h @ Wqkv + bqkv
    gemm64<0><<<dim3(2304 / 64, (MROWS + 63) / 64), 256, 0, stream>>>(
        hbuf, wqkvT, bqkv, qkv, nullptr, MROWS, 2304, 768);
    // 4. attention
    attn_kernel<<<dim3(19, BATCH * HEADS), 256, 0, stream>>>(qkv, attno);
    // 5. o-proj + residual: out = x + attno @ wo + bo
    gemm64<1><<<dim3(768 / 64, (MROWS + 63) / 64), 256, 0, stream>>>(
        attno, woT, bo, out, x, MROWS, 768, 768);
    // 6. LN2 (reads d_out) -> h2
    ln_bf16<<<MROWS, 256, 0, stream>>>(out, ln2_g, ln2_b, h2);
    // 7. MLP1 + gelu: mid = gelu(h2 @ w1 + b1)
    gemm64<2><<<dim3(3072 / 64, (MROWS + 63) / 64), 256, 0, stream>>>(
        h2, w1T, b1, mid, nullptr, MROWS, 3072, 768);
    // 8. MLP2 + residual in-place: out += mid @ w2 + b2
    gemm64<1><<<dim3(768 / 64, (MROWS + 63) / 64), 256, 0, stream>>>(
        mid, w2T, b2, out, out, MROWS, 768, 3072);
}